// Round 6
// baseline (187.445 us; speedup 1.0000x reference)
//
#include <hip/hip_runtime.h>
#include <hip/hip_cooperative_groups.h>
#include <math.h>

namespace cg = cooperative_groups;

#define N 4096
#define B 2048
#define RANK 4
#define ALPHA 0.8862269254527580f   // sqrt(pi)/2
#define INV_N (1.0f / 4096.0f)

#define NBLK 256                    // == CU count: 1 block/CU, co-resident
#define NTHR 512
#define RPB (N / NBLK)              // 16 rows per block (phases 1 and 3)
#define P (5 * B)                   // partial plane = 10240 floats
#define STRIPE 64                   // phase-2 column stripe
#define NSTRIPE (P / STRIPE)        // 160 active blocks in phase 2
#define GRP 8                       // split-groups per stripe
#define SPG (NBLK / GRP)            // 32 splits per group

// __builtin_nontemporal_* requires ext_vector_type, not HIP_vector_type
typedef float vf4 __attribute__((ext_vector_type(4)));

// ---------------------------------------------------------------------------
// Single cooperative kernel, 3 phases:
//  P1: block = 16 whole rows (128 KB contiguous slab of h). Thread t owns
//      cols 4t..4t+3; 16 unrolled nontemporal vf4 loads; rank-4(+z) fma into
//      regs with v/z broadcast from LDS; write partials[split][5][B].
//  P2: 160 blocks; block j owns a 64-col stripe of the [5][B] plane.
//      8 waves each sum 32 splits (256 B coalesced per wave-iter), LDS tree
//      over the 8 groups -> sfin[4][B] + y[B] (scaled).
//  P3: block = 16 rows again; s/x hoisted per thread; u/m broadcast;
//      16 nontemporal vf4 stores (128 KB contiguous slab of h_new).
// grid.sync() between phases supplies the device-scope fence (XCD-safe).
// ---------------------------------------------------------------------------
__global__ void __launch_bounds__(NTHR) k_fused(
    const float* __restrict__ x, const float* __restrict__ h,
    const float* __restrict__ m, const float* __restrict__ u,
    const float* __restrict__ v, const float* __restrict__ z,
    float* __restrict__ y, float* __restrict__ hnew,
    float* __restrict__ partials, float* __restrict__ sfin) {
  cg::grid_group grid = cg::this_grid();
  const int tid = threadIdx.x;
  const int bid = blockIdx.x;

  // ---------------- phase 1: slab partials ----------------
  {
    __shared__ float lv[RPB * RANK];  // 64 floats
    __shared__ float lz[RPB];
    const int row0 = bid * RPB;
    if (tid < RPB * RANK) {
      lv[tid] = v[row0 * RANK + tid];
    } else if (tid < RPB * RANK + RPB) {
      lz[tid - RPB * RANK] = z[row0 + (tid - RPB * RANK)];
    }
    __syncthreads();

    vf4 a0 = {0.f, 0.f, 0.f, 0.f};
    vf4 a1 = a0, a2 = a0, a3 = a0, a4 = a0;
    const float* hp = h + (size_t)row0 * B + tid * 4;
#pragma unroll
    for (int r = 0; r < RPB; ++r) {
      const vf4 hv =
          __builtin_nontemporal_load((const vf4*)(hp + (size_t)r * B));
      vf4 p;
      p.x = erff(ALPHA * hv.x);
      p.y = erff(ALPHA * hv.y);
      p.z = erff(ALPHA * hv.z);
      p.w = erff(ALPHA * hv.w);
      const float v0 = lv[r * 4 + 0], v1 = lv[r * 4 + 1];
      const float v2 = lv[r * 4 + 2], v3 = lv[r * 4 + 3];
      const float zr = lz[r];
      a0.x = fmaf(v0, p.x, a0.x); a0.y = fmaf(v0, p.y, a0.y);
      a0.z = fmaf(v0, p.z, a0.z); a0.w = fmaf(v0, p.w, a0.w);
      a1.x = fmaf(v1, p.x, a1.x); a1.y = fmaf(v1, p.y, a1.y);
      a1.z = fmaf(v1, p.z, a1.z); a1.w = fmaf(v1, p.w, a1.w);
      a2.x = fmaf(v2, p.x, a2.x); a2.y = fmaf(v2, p.y, a2.y);
      a2.z = fmaf(v2, p.z, a2.z); a2.w = fmaf(v2, p.w, a2.w);
      a3.x = fmaf(v3, p.x, a3.x); a3.y = fmaf(v3, p.y, a3.y);
      a3.z = fmaf(v3, p.z, a3.z); a3.w = fmaf(v3, p.w, a3.w);
      a4.x = fmaf(zr, p.x, a4.x); a4.y = fmaf(zr, p.y, a4.y);
      a4.z = fmaf(zr, p.z, a4.z); a4.w = fmaf(zr, p.w, a4.w);
    }
    float* pp = partials + (size_t)bid * P + tid * 4;
    *(vf4*)(pp + 0 * B) = a0;
    *(vf4*)(pp + 1 * B) = a1;
    *(vf4*)(pp + 2 * B) = a2;
    *(vf4*)(pp + 3 * B) = a3;
    *(vf4*)(pp + 4 * B) = a4;
  }

  grid.sync();

  // ---------------- phase 2: split reduction ----------------
  if (bid < NSTRIPE) {
    __shared__ float red[GRP][STRIPE];
    const int c = tid & (STRIPE - 1);
    const int g = tid >> 6;  // 0..7, wave-uniform
    const float* pp = partials + (size_t)(g * SPG) * P + bid * STRIPE + c;
    float ssum = 0.f;
#pragma unroll 8
    for (int sp = 0; sp < SPG; ++sp)
      ssum += pp[(size_t)sp * P];
    red[g][c] = ssum;
    __syncthreads();
    if (tid < STRIPE) {
      float tot = 0.f;
#pragma unroll
      for (int g2 = 0; g2 < GRP; ++g2)
        tot += red[g2][tid];
      const int f = bid * STRIPE + tid;
      if (f < RANK * B)
        sfin[f] = tot;
      else
        y[f - RANK * B] = tot * INV_N;  // y = (z.T @ phi) / N
    }
  }

  grid.sync();

  // ---------------- phase 3: h_new update ----------------
  // h_new[n][b] = (sum_r u[n][r]*s[r][b])/N + m[n]*x[b]  (DT/TAU=1 -> h cancels)
  {
    const int row0 = bid * RPB;
    const int c0 = tid * 4;
    const vf4 s0 = *(const vf4*)(sfin + 0 * B + c0);
    const vf4 s1 = *(const vf4*)(sfin + 1 * B + c0);
    const vf4 s2 = *(const vf4*)(sfin + 2 * B + c0);
    const vf4 s3 = *(const vf4*)(sfin + 3 * B + c0);
    const vf4 xv = *(const vf4*)(x + c0);
    float* op = hnew + (size_t)row0 * B + c0;
#pragma unroll
    for (int i = 0; i < RPB; ++i) {
      const int n = row0 + i;
      const vf4 uv = *(const vf4*)(u + (size_t)n * RANK);
      const float mv = m[n];
      vf4 o;
      o.x = fmaf(mv, xv.x,
                 (s0.x * uv.x + s1.x * uv.y + s2.x * uv.z + s3.x * uv.w) * INV_N);
      o.y = fmaf(mv, xv.y,
                 (s0.y * uv.x + s1.y * uv.y + s2.y * uv.z + s3.y * uv.w) * INV_N);
      o.z = fmaf(mv, xv.z,
                 (s0.z * uv.x + s1.z * uv.y + s2.z * uv.z + s3.z * uv.w) * INV_N);
      o.w = fmaf(mv, xv.w,
                 (s0.w * uv.x + s1.w * uv.y + s2.w * uv.z + s3.w * uv.w) * INV_N);
      __builtin_nontemporal_store(o, (vf4*)(op + (size_t)i * B));
    }
  }
}

// ---------------------------------------------------------------------------
extern "C" void kernel_launch(void* const* d_in, const int* in_sizes, int n_in,
                              void* d_out, int out_size, void* d_ws,
                              size_t ws_size, hipStream_t stream) {
  const float* x = (const float*)d_in[0];  // [1, B]
  const float* h = (const float*)d_in[1];  // [N, B]
  const float* m = (const float*)d_in[2];  // [N, 1]
  const float* u = (const float*)d_in[3];  // [N, RANK]
  const float* v = (const float*)d_in[4];  // [N, RANK]
  const float* z = (const float*)d_in[5];  // [N, 1]

  float* y = (float*)d_out;            // output 0: y [1, B]
  float* hnew = (float*)d_out + B;     // output 1: h_new [N, B]

  float* partials = (float*)d_ws;                   // [NBLK][5][B]  10.5 MB
  float* sfin = partials + (size_t)NBLK * P;        // [RANK][B]      32 KB

  void* args[] = {(void*)&x, (void*)&h, (void*)&m,    (void*)&u,
                  (void*)&v, (void*)&z, (void*)&y,    (void*)&hnew,
                  (void*)&partials, (void*)&sfin};
  hipLaunchCooperativeKernel((const void*)k_fused, dim3(NBLK), dim3(NTHR),
                             args, 0, stream);
}

// Round 7
// 107.835 us; speedup vs baseline: 1.7383x; 1.7383x over previous
//
#include <hip/hip_runtime.h>
#include <math.h>

#define N 4096
#define B 2048
#define RANK 4
#define ALPHA 0.8862269254527580f   // sqrt(pi)/2
#define INV_N (1.0f / 4096.0f)

#define RPB1 8                      // rows per block, kernel 1
#define SPLITS (N / RPB1)           // 512 partial splits
#define P (5 * B)                   // one partial plane = 10240 floats
#define STRIPE 64                   // kernel-2 column stripe
#define GRP 8                       // split-groups per stripe
#define SPG (SPLITS / GRP)          // 64 splits per group
#define RPB3 4                      // rows per block, kernel 3

// __builtin_nontemporal_* requires ext_vector_type, not HIP_vector_type
typedef float vf4 __attribute__((ext_vector_type(4)));

// ---------------------------------------------------------------------------
// Kernel 1: rank-4 (+z) partial reduction.
// 512 blocks x 512 thr -> 2 blocks/CU, 16 waves/CU (2x R5: latency-hiding
// fix; every prior 8-wave/CU variant plateaued at ~500-850 GB/s).
// Block owns 8 whole rows = 64 KB contiguous of h; thread t owns cols
// 4t..4t+3; 8 unrolled PLAIN vf4 loads (h is L3-resident after the harness
// restore -- no nt hint). v/z broadcast from LDS.
// Writes partials[split][5][B] coalesced.
// ---------------------------------------------------------------------------
__global__ __launch_bounds__(512) void k_reduce_partial(
    const float* __restrict__ h, const float* __restrict__ v,
    const float* __restrict__ z, float* __restrict__ partials) {
  __shared__ float lv[RPB1 * RANK];  // 32 floats
  __shared__ float lz[RPB1];
  const int tid = threadIdx.x;
  const int row0 = blockIdx.x * RPB1;

  if (tid < RPB1 * RANK) {
    lv[tid] = v[row0 * RANK + tid];
  } else if (tid < RPB1 * RANK + RPB1) {
    lz[tid - RPB1 * RANK] = z[row0 + (tid - RPB1 * RANK)];
  }
  __syncthreads();

  vf4 a0 = {0.f, 0.f, 0.f, 0.f};
  vf4 a1 = a0, a2 = a0, a3 = a0, a4 = a0;

  const float* hp = h + (size_t)row0 * B + tid * 4;
#pragma unroll
  for (int r = 0; r < RPB1; ++r) {
    const vf4 hv = *(const vf4*)(hp + (size_t)r * B);
    vf4 p;
    p.x = erff(ALPHA * hv.x);
    p.y = erff(ALPHA * hv.y);
    p.z = erff(ALPHA * hv.z);
    p.w = erff(ALPHA * hv.w);
    const float v0 = lv[r * 4 + 0], v1 = lv[r * 4 + 1];
    const float v2 = lv[r * 4 + 2], v3 = lv[r * 4 + 3];
    const float zr = lz[r];
    a0.x = fmaf(v0, p.x, a0.x); a0.y = fmaf(v0, p.y, a0.y);
    a0.z = fmaf(v0, p.z, a0.z); a0.w = fmaf(v0, p.w, a0.w);
    a1.x = fmaf(v1, p.x, a1.x); a1.y = fmaf(v1, p.y, a1.y);
    a1.z = fmaf(v1, p.z, a1.z); a1.w = fmaf(v1, p.w, a1.w);
    a2.x = fmaf(v2, p.x, a2.x); a2.y = fmaf(v2, p.y, a2.y);
    a2.z = fmaf(v2, p.z, a2.z); a2.w = fmaf(v2, p.w, a2.w);
    a3.x = fmaf(v3, p.x, a3.x); a3.y = fmaf(v3, p.y, a3.y);
    a3.z = fmaf(v3, p.z, a3.z); a3.w = fmaf(v3, p.w, a3.w);
    a4.x = fmaf(zr, p.x, a4.x); a4.y = fmaf(zr, p.y, a4.y);
    a4.z = fmaf(zr, p.z, a4.z); a4.w = fmaf(zr, p.w, a4.w);
  }

  float* pp = partials + (size_t)blockIdx.x * P + tid * 4;
  *(vf4*)(pp + 0 * B) = a0;
  *(vf4*)(pp + 1 * B) = a1;
  *(vf4*)(pp + 2 * B) = a2;
  *(vf4*)(pp + 3 * B) = a3;
  *(vf4*)(pp + 4 * B) = a4;
}

// ---------------------------------------------------------------------------
// Kernel 2 (merged a+b): 512 splits -> sfin[4][B] + y[B], one kernel.
// 160 blocks x 512 thr; block owns a 64-col stripe of the [5][B] plane.
// Wave-group g (tid>>6) sums SPG=64 splits (256 B coalesced per iter,
// unroll-8 independent loads), LDS tree [8][64] (2-way bank alias = free),
// 64 threads write the stripe. 21 MB read from L2/L3.
// ---------------------------------------------------------------------------
__global__ __launch_bounds__(512) void k_reduce_final(
    const float* __restrict__ partials, float* __restrict__ sfin,
    float* __restrict__ y) {
  __shared__ float red[GRP][STRIPE];
  const int c = threadIdx.x & (STRIPE - 1);
  const int g = threadIdx.x >> 6;  // wave-uniform, 0..7
  const int f0 = blockIdx.x * STRIPE;
  const float* pp = partials + (size_t)(g * SPG) * P + f0 + c;
  float ssum = 0.f;
#pragma unroll 8
  for (int sp = 0; sp < SPG; ++sp)
    ssum += pp[(size_t)sp * P];
  red[g][c] = ssum;
  __syncthreads();
  if (threadIdx.x < STRIPE) {
    float tot = 0.f;
#pragma unroll
    for (int g2 = 0; g2 < GRP; ++g2)
      tot += red[g2][threadIdx.x];
    const int f = f0 + threadIdx.x;
    if (f < RANK * B)
      sfin[f] = tot;
    else
      y[f - RANK * B] = tot * INV_N;  // y = (z.T @ phi) / N
  }
}

// ---------------------------------------------------------------------------
// Kernel 3: h_new[n][b] = (sum_r u[n][r]*s[r][b])/N + m[n]*x[b]
// (DT/TAU = 1 -> h cancels exactly; h is never read.)
// 1024 blocks x 256 thr (4 blocks/CU, 16 waves/CU); block owns 4 whole rows
// = 32 KB contiguous nontemporal store slab. Thread t owns cols 4t and
// 4t+1024; s/x hoisted; u/m broadcast loads (wave-uniform n).
// ---------------------------------------------------------------------------
__global__ __launch_bounds__(256) void k_update(
    const float* __restrict__ sfin, const float* __restrict__ u,
    const float* __restrict__ m, const float* __restrict__ x,
    float* __restrict__ hnew) {
  const int tid = threadIdx.x;
  const int row0 = blockIdx.x * RPB3;
  const int c0 = tid * 4;

  const vf4 sA0 = *(const vf4*)(sfin + 0 * B + c0);
  const vf4 sA1 = *(const vf4*)(sfin + 1 * B + c0);
  const vf4 sA2 = *(const vf4*)(sfin + 2 * B + c0);
  const vf4 sA3 = *(const vf4*)(sfin + 3 * B + c0);
  const vf4 xa  = *(const vf4*)(x + c0);
  const vf4 sB0 = *(const vf4*)(sfin + 0 * B + c0 + 1024);
  const vf4 sB1 = *(const vf4*)(sfin + 1 * B + c0 + 1024);
  const vf4 sB2 = *(const vf4*)(sfin + 2 * B + c0 + 1024);
  const vf4 sB3 = *(const vf4*)(sfin + 3 * B + c0 + 1024);
  const vf4 xb  = *(const vf4*)(x + c0 + 1024);

  float* op = hnew + (size_t)row0 * B + c0;
#pragma unroll
  for (int i = 0; i < RPB3; ++i) {
    const int n = row0 + i;
    const vf4 uv = *(const vf4*)(u + (size_t)n * RANK);
    const float mv = m[n];
    vf4 oA, oB;
    oA.x = fmaf(mv, xa.x,
                (sA0.x * uv.x + sA1.x * uv.y + sA2.x * uv.z + sA3.x * uv.w) * INV_N);
    oA.y = fmaf(mv, xa.y,
                (sA0.y * uv.x + sA1.y * uv.y + sA2.y * uv.z + sA3.y * uv.w) * INV_N);
    oA.z = fmaf(mv, xa.z,
                (sA0.z * uv.x + sA1.z * uv.y + sA2.z * uv.z + sA3.z * uv.w) * INV_N);
    oA.w = fmaf(mv, xa.w,
                (sA0.w * uv.x + sA1.w * uv.y + sA2.w * uv.z + sA3.w * uv.w) * INV_N);
    oB.x = fmaf(mv, xb.x,
                (sB0.x * uv.x + sB1.x * uv.y + sB2.x * uv.z + sB3.x * uv.w) * INV_N);
    oB.y = fmaf(mv, xb.y,
                (sB0.y * uv.x + sB1.y * uv.y + sB2.y * uv.z + sB3.y * uv.w) * INV_N);
    oB.z = fmaf(mv, xb.z,
                (sB0.z * uv.x + sB1.z * uv.y + sB2.z * uv.z + sB3.z * uv.w) * INV_N);
    oB.w = fmaf(mv, xb.w,
                (sB0.w * uv.x + sB1.w * uv.y + sB2.w * uv.z + sB3.w * uv.w) * INV_N);
    __builtin_nontemporal_store(oA, (vf4*)(op + (size_t)i * B));
    __builtin_nontemporal_store(oB, (vf4*)(op + (size_t)i * B + 1024));
  }
}

// ---------------------------------------------------------------------------
extern "C" void kernel_launch(void* const* d_in, const int* in_sizes, int n_in,
                              void* d_out, int out_size, void* d_ws,
                              size_t ws_size, hipStream_t stream) {
  const float* x = (const float*)d_in[0];  // [1, B]
  const float* h = (const float*)d_in[1];  // [N, B]
  const float* m = (const float*)d_in[2];  // [N, 1]
  const float* u = (const float*)d_in[3];  // [N, RANK]
  const float* v = (const float*)d_in[4];  // [N, RANK]
  const float* z = (const float*)d_in[5];  // [N, 1]

  float* y = (float*)d_out;            // output 0: y [1, B]
  float* hnew = (float*)d_out + B;     // output 1: h_new [N, B]

  float* partials = (float*)d_ws;                   // [SPLITS][5][B]  21 MB
  float* sfin = partials + (size_t)SPLITS * P;      // [RANK][B]       32 KB

  k_reduce_partial<<<SPLITS, 512, 0, stream>>>(h, v, z, partials);
  k_reduce_final<<<P / STRIPE, 512, 0, stream>>>(partials, sfin, y);
  k_update<<<N / RPB3, 256, 0, stream>>>(sfin, u, m, x, hnew);
}

// Round 8
// 106.231 us; speedup vs baseline: 1.7645x; 1.0151x over previous
//
#include <hip/hip_runtime.h>
#include <math.h>

#define N 4096
#define B 2048
#define RANK 4
#define ALPHA 0.8862269254527580f   // sqrt(pi)/2
#define INV_N (1.0f / 4096.0f)

#define RPB1 8                      // rows per block, kernel 1
#define SPLITS (N / RPB1)           // 512 partial splits
#define P (5 * B)                   // one partial plane = 10240 floats
#define STRIPE 64                   // kernel-2 column stripe
#define GRP 8                       // split-groups per stripe
#define SPG (SPLITS / GRP)          // 64 splits per group
#define RPB3 4                      // rows per block, kernel 3

// __builtin_nontemporal_* requires ext_vector_type, not HIP_vector_type
typedef float vf4 __attribute__((ext_vector_type(4)));

// Branchless Winitzki erf: erf(t) ~= sign(t)*sqrt(1-exp(-t^2*(4/pi+a t^2)/(1+a t^2)))
// a = 8(pi-3)/(3pi(4-pi)); max abs err ~2.5e-4 -> <=1e-3 in h_new (thr 0.24).
// ocml erff is branchy (poly |t|<1, exp path else): with h~N(0,1) every wave
// runs BOTH divergent paths. This is ~11 branchless ops, 3 fast-trans.
__device__ __forceinline__ float erf_fast(float t) {
  const float A = 0.140012288f;
  const float FP = 1.2732395447f;  // 4/pi
  float t2 = t * t;
  float num = fmaf(A, t2, FP);
  float den = fmaf(A, t2, 1.0f);
  float r = t2 * num * __builtin_amdgcn_rcpf(den);
  float e = __expf(-r);
  float s = __builtin_amdgcn_sqrtf(fmaxf(1.0f - e, 0.0f));
  return copysignf(s, t);
}

// ---------------------------------------------------------------------------
// Kernel 1: rank-4 (+z) partial reduction.
// 512 blocks x 512 thr (2 blocks/CU, 16 waves/CU). Block owns 8 whole rows =
// 64 KB contiguous of h; thread t owns cols 4t..4t+3; 8 unrolled vf4 loads.
// v/z read directly with block-uniform indices -> compiler emits hoisted
// s_loads (no LDS, no __syncthreads, no lgkm deps in the loop).
// ---------------------------------------------------------------------------
__global__ __launch_bounds__(512) void k_reduce_partial(
    const float* __restrict__ h, const float* __restrict__ v,
    const float* __restrict__ z, float* __restrict__ partials) {
  const int tid = threadIdx.x;
  const int row0 = blockIdx.x * RPB1;

  vf4 a0 = {0.f, 0.f, 0.f, 0.f};
  vf4 a1 = a0, a2 = a0, a3 = a0, a4 = a0;

  const float* hp = h + (size_t)row0 * B + tid * 4;
#pragma unroll
  for (int r = 0; r < RPB1; ++r) {
    const vf4 hv = *(const vf4*)(hp + (size_t)r * B);
    vf4 p;
    p.x = erf_fast(ALPHA * hv.x);
    p.y = erf_fast(ALPHA * hv.y);
    p.z = erf_fast(ALPHA * hv.z);
    p.w = erf_fast(ALPHA * hv.w);
    const float v0 = v[(row0 + r) * RANK + 0];
    const float v1 = v[(row0 + r) * RANK + 1];
    const float v2 = v[(row0 + r) * RANK + 2];
    const float v3 = v[(row0 + r) * RANK + 3];
    const float zr = z[row0 + r];
    a0.x = fmaf(v0, p.x, a0.x); a0.y = fmaf(v0, p.y, a0.y);
    a0.z = fmaf(v0, p.z, a0.z); a0.w = fmaf(v0, p.w, a0.w);
    a1.x = fmaf(v1, p.x, a1.x); a1.y = fmaf(v1, p.y, a1.y);
    a1.z = fmaf(v1, p.z, a1.z); a1.w = fmaf(v1, p.w, a1.w);
    a2.x = fmaf(v2, p.x, a2.x); a2.y = fmaf(v2, p.y, a2.y);
    a2.z = fmaf(v2, p.z, a2.z); a2.w = fmaf(v2, p.w, a2.w);
    a3.x = fmaf(v3, p.x, a3.x); a3.y = fmaf(v3, p.y, a3.y);
    a3.z = fmaf(v3, p.z, a3.z); a3.w = fmaf(v3, p.w, a3.w);
    a4.x = fmaf(zr, p.x, a4.x); a4.y = fmaf(zr, p.y, a4.y);
    a4.z = fmaf(zr, p.z, a4.z); a4.w = fmaf(zr, p.w, a4.w);
  }

  float* pp = partials + (size_t)blockIdx.x * P + tid * 4;
  *(vf4*)(pp + 0 * B) = a0;
  *(vf4*)(pp + 1 * B) = a1;
  *(vf4*)(pp + 2 * B) = a2;
  *(vf4*)(pp + 3 * B) = a3;
  *(vf4*)(pp + 4 * B) = a4;
}

// ---------------------------------------------------------------------------
// Kernel 2: 512 splits -> sfin[4][B] + y[B], one kernel.
// 160 blocks x 512 thr; block owns a 64-col stripe of the [5][B] plane.
// Wave-group g (tid>>6) sums SPG=64 splits (256 B coalesced per iter,
// unroll-8 independent loads), LDS tree [8][64], 64 threads write stripe.
// ---------------------------------------------------------------------------
__global__ __launch_bounds__(512) void k_reduce_final(
    const float* __restrict__ partials, float* __restrict__ sfin,
    float* __restrict__ y) {
  __shared__ float red[GRP][STRIPE];
  const int c = threadIdx.x & (STRIPE - 1);
  const int g = threadIdx.x >> 6;  // wave-uniform, 0..7
  const int f0 = blockIdx.x * STRIPE;
  const float* pp = partials + (size_t)(g * SPG) * P + f0 + c;
  float ssum = 0.f;
#pragma unroll 8
  for (int sp = 0; sp < SPG; ++sp)
    ssum += pp[(size_t)sp * P];
  red[g][c] = ssum;
  __syncthreads();
  if (threadIdx.x < STRIPE) {
    float tot = 0.f;
#pragma unroll
    for (int g2 = 0; g2 < GRP; ++g2)
      tot += red[g2][threadIdx.x];
    const int f = f0 + threadIdx.x;
    if (f < RANK * B)
      sfin[f] = tot;
    else
      y[f - RANK * B] = tot * INV_N;  // y = (z.T @ phi) / N
  }
}

// ---------------------------------------------------------------------------
// Kernel 3: h_new[n][b] = (sum_r u[n][r]*s[r][b])/N + m[n]*x[b]
// (DT/TAU = 1 -> h cancels exactly; h is never read.)
// 1024 blocks x 256 thr; block owns 4 whole rows = 32 KB contiguous
// nontemporal store slab. Thread t owns cols 4t and 4t+1024.
// ---------------------------------------------------------------------------
__global__ __launch_bounds__(256) void k_update(
    const float* __restrict__ sfin, const float* __restrict__ u,
    const float* __restrict__ m, const float* __restrict__ x,
    float* __restrict__ hnew) {
  const int tid = threadIdx.x;
  const int row0 = blockIdx.x * RPB3;
  const int c0 = tid * 4;

  const vf4 sA0 = *(const vf4*)(sfin + 0 * B + c0);
  const vf4 sA1 = *(const vf4*)(sfin + 1 * B + c0);
  const vf4 sA2 = *(const vf4*)(sfin + 2 * B + c0);
  const vf4 sA3 = *(const vf4*)(sfin + 3 * B + c0);
  const vf4 xa  = *(const vf4*)(x + c0);
  const vf4 sB0 = *(const vf4*)(sfin + 0 * B + c0 + 1024);
  const vf4 sB1 = *(const vf4*)(sfin + 1 * B + c0 + 1024);
  const vf4 sB2 = *(const vf4*)(sfin + 2 * B + c0 + 1024);
  const vf4 sB3 = *(const vf4*)(sfin + 3 * B + c0 + 1024);
  const vf4 xb  = *(const vf4*)(x + c0 + 1024);

  float* op = hnew + (size_t)row0 * B + c0;
#pragma unroll
  for (int i = 0; i < RPB3; ++i) {
    const int n = row0 + i;
    const vf4 uv = *(const vf4*)(u + (size_t)n * RANK);
    const float mv = m[n];
    vf4 oA, oB;
    oA.x = fmaf(mv, xa.x,
                (sA0.x * uv.x + sA1.x * uv.y + sA2.x * uv.z + sA3.x * uv.w) * INV_N);
    oA.y = fmaf(mv, xa.y,
                (sA0.y * uv.x + sA1.y * uv.y + sA2.y * uv.z + sA3.y * uv.w) * INV_N);
    oA.z = fmaf(mv, xa.z,
                (sA0.z * uv.x + sA1.z * uv.y + sA2.z * uv.z + sA3.z * uv.w) * INV_N);
    oA.w = fmaf(mv, xa.w,
                (sA0.w * uv.x + sA1.w * uv.y + sA2.w * uv.z + sA3.w * uv.w) * INV_N);
    oB.x = fmaf(mv, xb.x,
                (sB0.x * uv.x + sB1.x * uv.y + sB2.x * uv.z + sB3.x * uv.w) * INV_N);
    oB.y = fmaf(mv, xb.y,
                (sB0.y * uv.x + sB1.y * uv.y + sB2.y * uv.z + sB3.y * uv.w) * INV_N);
    oB.z = fmaf(mv, xb.z,
                (sB0.z * uv.x + sB1.z * uv.y + sB2.z * uv.z + sB3.z * uv.w) * INV_N);
    oB.w = fmaf(mv, xb.w,
                (sB0.w * uv.x + sB1.w * uv.y + sB2.w * uv.z + sB3.w * uv.w) * INV_N);
    __builtin_nontemporal_store(oA, (vf4*)(op + (size_t)i * B));
    __builtin_nontemporal_store(oB, (vf4*)(op + (size_t)i * B + 1024));
  }
}

// ---------------------------------------------------------------------------
extern "C" void kernel_launch(void* const* d_in, const int* in_sizes, int n_in,
                              void* d_out, int out_size, void* d_ws,
                              size_t ws_size, hipStream_t stream) {
  const float* x = (const float*)d_in[0];  // [1, B]
  const float* h = (const float*)d_in[1];  // [N, B]
  const float* m = (const float*)d_in[2];  // [N, 1]
  const float* u = (const float*)d_in[3];  // [N, RANK]
  const float* v = (const float*)d_in[4];  // [N, RANK]
  const float* z = (const float*)d_in[5];  // [N, 1]

  float* y = (float*)d_out;            // output 0: y [1, B]
  float* hnew = (float*)d_out + B;     // output 1: h_new [N, B]

  float* partials = (float*)d_ws;                   // [SPLITS][5][B]  21 MB
  float* sfin = partials + (size_t)SPLITS * P;      // [RANK][B]       32 KB

  k_reduce_partial<<<SPLITS, 512, 0, stream>>>(h, v, z, partials);
  k_reduce_final<<<P / STRIPE, 512, 0, stream>>>(partials, sfin, y);
  k_update<<<N / RPB3, 256, 0, stream>>>(sfin, u, m, x, hnew);
}